// Round 2
// baseline (409.412 us; speedup 1.0000x reference)
//
#include <hip/hip_runtime.h>
#include <hip/hip_fp16.h>
#include <stdint.h>

#define DEVI __device__ __forceinline__

using f16x8 = __attribute__((ext_vector_type(8))) _Float16;
using f32x4 = __attribute__((ext_vector_type(4))) float;

// global -> LDS direct copy, 16B per lane. LDS dest is wave-uniform base;
// HW writes base + lane*16 (guide m104/m108). Global src is per-lane.
DEVI void gload_lds16(const void* g, void* lds) {
  using GP = const __attribute__((address_space(1))) void*;
  using LP = __attribute__((address_space(3))) void*;
  __builtin_amdgcn_global_load_lds((GP)g, (LP)lds, 16, 0, 0);
}

DEVI uint32_t pack2h(float a, float b) {
  return (uint32_t)__half_as_ushort(__float2half(a)) |
         ((uint32_t)__half_as_ushort(__float2half(b)) << 16);
}

// ---------------- f32 -> f16 convert (vectorized, G13) ----------------
__global__ __launch_bounds__(256) void cvt_f32_f16(const float* __restrict__ in,
                                                   __half* __restrict__ out, int n8) {
  int i = blockIdx.x * 256 + threadIdx.x;
  if (i >= n8) return;
  float4 a = ((const float4*)in)[i * 2];
  float4 b = ((const float4*)in)[i * 2 + 1];
  uint4 u;
  u.x = pack2h(a.x, a.y);
  u.y = pack2h(a.z, a.w);
  u.z = pack2h(b.x, b.y);
  u.w = pack2h(b.z, b.w);
  ((uint4*)out)[i] = u;
}

// ---------------- GEMM: C[M][N] = A[M][K] * B[N][K]^T, f16 in, f32 acc ----------------
// 128x128 tile, BK=32, 4 waves (2x2), 16x16x32 f16 MFMA.
// LDS is XOR-swizzled (slot ^= row&3 within 64B rows) with pre-swizzled global
// source so global_load_lds (linear dest) + swizzled ds_read both work (rule 21).
DEVI void store_c(__half* p, float v) { *p = __float2half(v); }
DEVI void store_c(float* p, float v) { *p = v; }

template <typename OT>
__global__ __launch_bounds__(256) void gemm_bt(const __half* __restrict__ A,
                                               const __half* __restrict__ B,
                                               OT* __restrict__ C, int M, int N, int K) {
  __shared__ __half As[128 * 32];
  __shared__ __half Bs[128 * 32];
  const int tid = threadIdx.x;
  const int w = tid >> 6, l = tid & 63;
  const int wm = w >> 1, wn = w & 1;
  const int m16 = l & 15, g = l >> 4;
  const int row0 = blockIdx.y * 128, col0 = blockIdx.x * 128;

  // staging coords: chunk c covers LDS bytes [c*1024, c*1024+1024)
  // lane l -> row = c*16 + (l>>2), 16B slot = l&3; source k-slot = slot ^ (row&3)
  const int srow = l >> 2;
  const int ks = ((l & 3) ^ (srow & 3)) * 8;  // f16 elements

  f32x4 acc[4][4] = {};

  for (int kt = 0; kt < K; kt += 32) {
    __syncthreads();
#pragma unroll
    for (int i = 0; i < 2; ++i) {
      int c = w * 2 + i;
      int r = c * 16 + srow;
      gload_lds16(A + (size_t)(row0 + r) * K + kt + ks, (char*)As + c * 1024);
      gload_lds16(B + (size_t)(col0 + r) * K + kt + ks, (char*)Bs + c * 1024);
    }
    __syncthreads();
    f16x8 aF[4], bF[4];
#pragma unroll
    for (int mi = 0; mi < 4; ++mi) {
      int r = wm * 64 + mi * 16 + m16;
      aF[mi] = *(const f16x8*)((const char*)As + r * 64 + ((g << 4) ^ ((r & 3) << 4)));
    }
#pragma unroll
    for (int ni = 0; ni < 4; ++ni) {
      int r = wn * 64 + ni * 16 + m16;
      bF[ni] = *(const f16x8*)((const char*)Bs + r * 64 + ((g << 4) ^ ((r & 3) << 4)));
    }
#pragma unroll
    for (int mi = 0; mi < 4; ++mi)
#pragma unroll
      for (int ni = 0; ni < 4; ++ni)
        acc[mi][ni] = __builtin_amdgcn_mfma_f32_16x16x32_f16(aF[mi], bF[ni], acc[mi][ni], 0, 0, 0);
  }

  // C/D layout: col = lane&15, row = (lane>>4)*4 + reg (guide m89)
#pragma unroll
  for (int mi = 0; mi < 4; ++mi)
#pragma unroll
    for (int ni = 0; ni < 4; ++ni)
#pragma unroll
      for (int j = 0; j < 4; ++j) {
        int r = row0 + wm * 64 + mi * 16 + g * 4 + j;
        int cc = col0 + wn * 64 + ni * 16 + m16;
        store_c(&C[(size_t)r * N + cc], acc[mi][ni][j]);
      }
}

// ---------------- RoPE + scatter to per-head layout ----------------
// qkv: [8192][3072] f16 (row = b*2048+n, col = s*1024 + h*64 + d)
// outputs: qr/kr/vr [64 bh][2048][64] f16; q pre-scaled by log2(e)/8 so the
// attention kernel can use exp2 with no per-element scale.
__global__ __launch_bounds__(256) void rope_scatter(const __half* __restrict__ qkv,
                                                    const float* __restrict__ rot,
                                                    __half* __restrict__ qr,
                                                    __half* __restrict__ kr,
                                                    __half* __restrict__ vr) {
  int t = blockIdx.x * 256 + threadIdx.x;  // 3*64*2048 threads
  int s = t >> 17;
  int rem = t & 131071;
  int bh = rem >> 11;
  int n = rem & 2047;
  int b = bh >> 4, h = bh & 15;
  const __half* src = qkv + (size_t)(b * 2048 + n) * 3072 + s * 1024 + h * 64;
  __half* dst = (s == 0 ? qr : (s == 1 ? kr : vr)) + ((size_t)bh * 2048 + n) * 64;
  if (s == 2) {
    // copy the FULL 64-half (128B) row — 8 uint4, not 4 (this was the round-1 bug)
#pragma unroll
    for (int c = 0; c < 8; ++c) ((uint4*)dst)[c] = ((const uint4*)src)[c];
    return;
  }
  const float sc = (s == 0) ? 0.18033688011112042f : 1.0f;  // log2(e)/sqrt(64)
  const float* rp = rot + n * 64;
#pragma unroll
  for (int c = 0; c < 4; ++c) {
    f16x8 lo = ((const f16x8*)src)[c];      // d = 8c .. 8c+7
    f16x8 hi = ((const f16x8*)src)[c + 4];  // d+32
    float ol[8], oh[8];
#pragma unroll
    for (int j = 0; j < 8; ++j) {
      int d = c * 8 + j;
      float tl = (float)lo[j], th = (float)hi[j];
      float s0, c0, s1, c1;
      __sincosf(rp[d], &s0, &c0);
      __sincosf(rp[d + 32], &s1, &c1);
      ol[j] = (tl * c0 - th * s0) * sc;
      oh[j] = (th * c1 + tl * s1) * sc;
    }
    uint4 ulo, uhi;
    ulo.x = pack2h(ol[0], ol[1]); ulo.y = pack2h(ol[2], ol[3]);
    ulo.z = pack2h(ol[4], ol[5]); ulo.w = pack2h(ol[6], ol[7]);
    uhi.x = pack2h(oh[0], oh[1]); uhi.y = pack2h(oh[2], oh[3]);
    uhi.z = pack2h(oh[4], oh[5]); uhi.w = pack2h(oh[6], oh[7]);
    ((uint4*)dst)[c] = ulo;
    ((uint4*)dst)[c + 4] = uhi;
  }
}

// ---------------- Flash attention fwd ----------------
// grid: 64 bh * 32 q-tiles; block 256 (4 waves), QBLK=64 (16 q-rows/wave), KVBLK=64.
// Scores/softmax in f32 (exp2 domain, scale folded into q). K tile via
// global_load_lds with XOR swizzle; V transposed into LDS (conflict-free);
// P round-trips through a per-wave swizzled LDS buffer (row stride 160B).
__global__ __launch_bounds__(256) void attn_fwd(const __half* __restrict__ qr,
                                                const __half* __restrict__ kr,
                                                const __half* __restrict__ vr,
                                                __half* __restrict__ out) {
  __shared__ __half Kt[64 * 64];
  __shared__ __half Vt[64 * 64];
  __shared__ __half Pl[4][16 * 80];

  const int bh = blockIdx.x >> 5;
  const int q0 = (blockIdx.x & 31) * 64;
  const int tid = threadIdx.x;
  const int w = tid >> 6, l = tid & 63;
  const int m16 = l & 15, g = l >> 4;
  const size_t headoff = (size_t)bh * 2048 * 64;

  // Q A-frags (rows = wave's 16 q rows), kept in registers for the whole block
  f16x8 qA[2];
  {
    const __half* qb = qr + headoff + (size_t)(q0 + w * 16 + m16) * 64 + g * 8;
    qA[0] = *(const f16x8*)qb;
    qA[1] = *(const f16x8*)(qb + 32);
  }

  f32x4 o[4] = {};
  float mreg[4] = {-1e30f, -1e30f, -1e30f, -1e30f};
  float lreg[4] = {0.f, 0.f, 0.f, 0.f};

  for (int kv0 = 0; kv0 < 2048; kv0 += 64) {
    __syncthreads();  // protect LDS from previous iteration's readers
    // ---- stage K tile [64 kv][64 d], XOR-swizzled (slot ^= row&7 within 128B rows)
    {
      const __half* kb = kr + headoff + (size_t)kv0 * 64;
#pragma unroll
      for (int i = 0; i < 2; ++i) {
        int c = w * 2 + i;
        int row = c * 8 + (l >> 3);
        int kslot = ((l & 7) ^ (l >> 3)) * 8;  // row&7 == l>>3
        gload_lds16(kb + (size_t)row * 64 + kslot, (char*)Kt + c * 1024);
      }
    }
    // ---- stage V transposed: Vt[d][kv], XOR-swizzled; conflict-free writes
    {
      const __half* vb = vr + headoff + (size_t)kv0 * 64;
#pragma unroll
      for (int i = 0; i < 2; ++i) {
        int d0 = w * 8 + i * 32;
        f16x8 vv = *(const f16x8*)(vb + (size_t)l * 64 + d0);
#pragma unroll
        for (int jj = 0; jj < 8; ++jj) {
          int d = d0 + jj;  // d&7 == jj
          int off = d * 128 + ((2 * l) ^ (jj << 4));
          *(_Float16*)((char*)Vt + off) = vv[jj];
        }
      }
    }
    __syncthreads();

    // ---- S = Q K^T  (S tile: 16 q rows x 64 kv cols per wave)
    f32x4 s[4] = {};
#pragma unroll
    for (int nt = 0; nt < 4; ++nt) {
      int row = nt * 16 + m16;
#pragma unroll
      for (int kk = 0; kk < 2; ++kk) {
        int bo = row * 128 + ((kk * 64 + g * 16) ^ ((row & 7) << 4));
        f16x8 kB = *(const f16x8*)((const char*)Kt + bo);
        s[nt] = __builtin_amdgcn_mfma_f32_16x16x32_f16(qA[kk], kB, s[nt], 0, 0, 0);
      }
    }

    // ---- online softmax (rows 4g+j live across lanes of 16-lane group g)
    float alpha[4];
#pragma unroll
    for (int j = 0; j < 4; ++j) {
      float mt = fmaxf(fmaxf(s[0][j], s[1][j]), fmaxf(s[2][j], s[3][j]));
      mt = fmaxf(mt, __shfl_xor(mt, 1));
      mt = fmaxf(mt, __shfl_xor(mt, 2));
      mt = fmaxf(mt, __shfl_xor(mt, 4));
      mt = fmaxf(mt, __shfl_xor(mt, 8));
      float mnew = fmaxf(mreg[j], mt);
      alpha[j] = exp2f(mreg[j] - mnew);
      mreg[j] = mnew;
    }
    float rs[4] = {0.f, 0.f, 0.f, 0.f};
#pragma unroll
    for (int nt = 0; nt < 4; ++nt)
#pragma unroll
      for (int j = 0; j < 4; ++j) {
        float p = exp2f(s[nt][j] - mreg[j]);
        s[nt][j] = p;
        rs[j] += p;
      }
#pragma unroll
    for (int j = 0; j < 4; ++j) {
      rs[j] += __shfl_xor(rs[j], 1);
      rs[j] += __shfl_xor(rs[j], 2);
      rs[j] += __shfl_xor(rs[j], 4);
      rs[j] += __shfl_xor(rs[j], 8);
      lreg[j] = lreg[j] * alpha[j] + rs[j];
    }
#pragma unroll
    for (int nt = 0; nt < 4; ++nt)
#pragma unroll
      for (int j = 0; j < 4; ++j) o[nt][j] *= alpha[j];

    // ---- P -> per-wave LDS (row stride 160B, XOR swizzle), then PV
    char* pw = (char*)Pl[w];
#pragma unroll
    for (int nt = 0; nt < 4; ++nt)
#pragma unroll
      for (int j = 0; j < 4; ++j) {
        int prow = g * 4 + j;
        int col = nt * 16 + m16;
        int bo = prow * 160 + ((2 * col) ^ ((prow & 7) << 4));
        *(__half*)(pw + bo) = __float2half(s[nt][j]);
      }
#pragma unroll
    for (int kk = 0; kk < 2; ++kk) {
      int bo = m16 * 160 + ((kk * 64 + g * 16) ^ ((m16 & 7) << 4));
      f16x8 pA = *(const f16x8*)(pw + bo);
#pragma unroll
      for (int nt = 0; nt < 4; ++nt) {
        int drow = nt * 16 + m16;
        int vo = drow * 128 + ((kk * 64 + g * 16) ^ ((drow & 7) << 4));
        f16x8 vB = *(const f16x8*)((const char*)Vt + vo);
        o[nt] = __builtin_amdgcn_mfma_f32_16x16x32_f16(pA, vB, o[nt], 0, 0, 0);
      }
    }
  }

  // ---- epilogue: normalize and store to [b][n][h*64+d]
  const int b = bh >> 4, h = bh & 15;
#pragma unroll
  for (int j = 0; j < 4; ++j) {
    float inv = 1.0f / lreg[j];
    int qrow = q0 + w * 16 + g * 4 + j;
    __half* orow = out + (size_t)(b * 2048 + qrow) * 1024 + h * 64;
#pragma unroll
    for (int nt = 0; nt < 4; ++nt)
      orow[nt * 16 + m16] = __float2half(o[nt][j] * inv);
  }
}

// ---------------- launch ----------------
extern "C" void kernel_launch(void* const* d_in, const int* in_sizes, int n_in,
                              void* d_out, int out_size, void* d_ws, size_t ws_size,
                              hipStream_t stream) {
  const float* x    = (const float*)d_in[0];  // [4,2048,1024]
  const float* rot  = (const float*)d_in[1];  // [2048,64]
  const float* wqkv = (const float*)d_in[2];  // [3072,1024]
  const float* wout = (const float*)d_in[3];  // [1024,1024]
  float* out = (float*)d_out;
  char* ws = (char*)d_ws;

  __half* xb    = (__half*)(ws + 0);               // 16 MB (dead after gemm1 -> reused as qr)
  __half* wqkvb = (__half*)(ws + (16ull << 20));   // 6 MB
  __half* woutb = (__half*)(ws + (22ull << 20));   // 2 MB
  __half* qkv   = (__half*)(ws + (24ull << 20));   // 48 MB (dead after rope -> reused as attn_out)
  __half* kr    = (__half*)(ws + (72ull << 20));   // 16 MB
  __half* vr    = (__half*)(ws + (88ull << 20));   // 16 MB; total 104 MB
  __half* qr    = xb;
  __half* ao    = qkv;

  cvt_f32_f16<<<4096, 256, 0, stream>>>(x, xb, 1048576);
  cvt_f32_f16<<<1536, 256, 0, stream>>>(wqkv, wqkvb, 393216);
  cvt_f32_f16<<<512, 256, 0, stream>>>(wout, woutb, 131072);
  // qkv = xb @ wqkvb^T   [8192,3072]
  gemm_bt<__half><<<dim3(24, 64), 256, 0, stream>>>(xb, wqkvb, qkv, 8192, 3072, 1024);
  rope_scatter<<<1536, 256, 0, stream>>>(qkv, rot, qr, kr, vr);
  attn_fwd<<<2048, 256, 0, stream>>>(qr, kr, vr, ao);
  // out = ao @ woutb^T   [8192,1024] f32
  gemm_bt<float><<<dim3(8, 64), 256, 0, stream>>>(ao, woutb, out, 8192, 1024, 1024);
}

// Round 3
// 363.709 us; speedup vs baseline: 1.1257x; 1.1257x over previous
//
#include <hip/hip_runtime.h>
#include <hip/hip_fp16.h>
#include <stdint.h>

#define DEVI __device__ __forceinline__

using f16x8 = __attribute__((ext_vector_type(8))) _Float16;
using f32x4 = __attribute__((ext_vector_type(4))) float;

// global -> LDS direct copy, 16B per lane. LDS dest is wave-uniform base;
// HW writes base + lane*16 (guide m104/m108). Global src is per-lane.
DEVI void gload_lds16(const void* g, void* lds) {
  using GP = const __attribute__((address_space(1))) void*;
  using LP = __attribute__((address_space(3))) void*;
  __builtin_amdgcn_global_load_lds((GP)g, (LP)lds, 16, 0, 0);
}

DEVI uint32_t pack2h(float a, float b) {
  return (uint32_t)__half_as_ushort(__float2half(a)) |
         ((uint32_t)__half_as_ushort(__float2half(b)) << 16);
}

// ---------------- f32 -> f16 convert (vectorized, G13) ----------------
__global__ __launch_bounds__(256) void cvt_f32_f16(const float* __restrict__ in,
                                                   __half* __restrict__ out, int n8) {
  int i = blockIdx.x * 256 + threadIdx.x;
  if (i >= n8) return;
  float4 a = ((const float4*)in)[i * 2];
  float4 b = ((const float4*)in)[i * 2 + 1];
  uint4 u;
  u.x = pack2h(a.x, a.y);
  u.y = pack2h(a.z, a.w);
  u.z = pack2h(b.x, b.y);
  u.w = pack2h(b.z, b.w);
  ((uint4*)out)[i] = u;
}

// ---------------- GEMM: C[M][N] = A[M][K] * B[N][K]^T, f16 in, f32 acc ----------------
// 128x128 tile, BK=32, 4 waves (2x2), 16x16x32 f16 MFMA. (unchanged from round 2)
DEVI void store_c(__half* p, float v) { *p = __float2half(v); }
DEVI void store_c(float* p, float v) { *p = v; }

template <typename OT>
__global__ __launch_bounds__(256) void gemm_bt(const __half* __restrict__ A,
                                               const __half* __restrict__ B,
                                               OT* __restrict__ C, int M, int N, int K) {
  __shared__ __half As[128 * 32];
  __shared__ __half Bs[128 * 32];
  const int tid = threadIdx.x;
  const int w = tid >> 6, l = tid & 63;
  const int wm = w >> 1, wn = w & 1;
  const int m16 = l & 15, g = l >> 4;
  const int row0 = blockIdx.y * 128, col0 = blockIdx.x * 128;

  const int srow = l >> 2;
  const int ks = ((l & 3) ^ (srow & 3)) * 8;  // f16 elements

  f32x4 acc[4][4] = {};

  for (int kt = 0; kt < K; kt += 32) {
    __syncthreads();
#pragma unroll
    for (int i = 0; i < 2; ++i) {
      int c = w * 2 + i;
      int r = c * 16 + srow;
      gload_lds16(A + (size_t)(row0 + r) * K + kt + ks, (char*)As + c * 1024);
      gload_lds16(B + (size_t)(col0 + r) * K + kt + ks, (char*)Bs + c * 1024);
    }
    __syncthreads();
    f16x8 aF[4], bF[4];
#pragma unroll
    for (int mi = 0; mi < 4; ++mi) {
      int r = wm * 64 + mi * 16 + m16;
      aF[mi] = *(const f16x8*)((const char*)As + r * 64 + ((g << 4) ^ ((r & 3) << 4)));
    }
#pragma unroll
    for (int ni = 0; ni < 4; ++ni) {
      int r = wn * 64 + ni * 16 + m16;
      bF[ni] = *(const f16x8*)((const char*)Bs + r * 64 + ((g << 4) ^ ((r & 3) << 4)));
    }
#pragma unroll
    for (int mi = 0; mi < 4; ++mi)
#pragma unroll
      for (int ni = 0; ni < 4; ++ni)
        acc[mi][ni] = __builtin_amdgcn_mfma_f32_16x16x32_f16(aF[mi], bF[ni], acc[mi][ni], 0, 0, 0);
  }

#pragma unroll
  for (int mi = 0; mi < 4; ++mi)
#pragma unroll
    for (int ni = 0; ni < 4; ++ni)
#pragma unroll
      for (int j = 0; j < 4; ++j) {
        int r = row0 + wm * 64 + mi * 16 + g * 4 + j;
        int cc = col0 + wn * 64 + ni * 16 + m16;
        store_c(&C[(size_t)r * N + cc], acc[mi][ni][j]);
      }
}

// ---------------- RoPE + scatter to per-head layout ----------------
// qkv: [8192][3072] f16 (row = b*2048+n, col = s*1024 + h*64 + d)
// outputs: qr/kr [64 bh][2048 n][64 d]; vr TRANSPOSED [64 bh][64 d][2048 n]
// (so attn can stage V via global_load_lds with no in-kernel transpose).
// q pre-scaled by log2(e)/8 so attn uses exp2 with no per-element scale.
__global__ __launch_bounds__(256) void rope_scatter(const __half* __restrict__ qkv,
                                                    const float* __restrict__ rot,
                                                    __half* __restrict__ qr,
                                                    __half* __restrict__ kr,
                                                    __half* __restrict__ vr) {
  int t = blockIdx.x * 256 + threadIdx.x;  // 3*64*2048 threads
  int s = t >> 17;
  int rem = t & 131071;
  int bh = rem >> 11;
  int n = rem & 2047;
  int b = bh >> 4, h = bh & 15;
  const __half* src = qkv + (size_t)(b * 2048 + n) * 3072 + s * 1024 + h * 64;
  if (s == 2) {
    // transposed store: vr[bh][d][n]; scalar stores, coalesced across lanes (consecutive n)
    __half* vdst = vr + ((size_t)bh * 64) * 2048 + n;
#pragma unroll
    for (int c = 0; c < 8; ++c) {
      f16x8 vv = ((const f16x8*)src)[c];
#pragma unroll
      for (int j = 0; j < 8; ++j) vdst[(size_t)(c * 8 + j) * 2048] = vv[j];
    }
    return;
  }
  __half* dst = (s == 0 ? qr : kr) + ((size_t)bh * 2048 + n) * 64;
  const float sc = (s == 0) ? 0.18033688011112042f : 1.0f;  // log2(e)/sqrt(64)
  const float* rp = rot + n * 64;
#pragma unroll
  for (int c = 0; c < 4; ++c) {
    f16x8 lo = ((const f16x8*)src)[c];      // d = 8c .. 8c+7
    f16x8 hi = ((const f16x8*)src)[c + 4];  // d+32
    float ol[8], oh[8];
#pragma unroll
    for (int j = 0; j < 8; ++j) {
      int d = c * 8 + j;
      float tl = (float)lo[j], th = (float)hi[j];
      float s0, c0, s1, c1;
      __sincosf(rp[d], &s0, &c0);
      __sincosf(rp[d + 32], &s1, &c1);
      ol[j] = (tl * c0 - th * s0) * sc;
      oh[j] = (th * c1 + tl * s1) * sc;
    }
    uint4 ulo, uhi;
    ulo.x = pack2h(ol[0], ol[1]); ulo.y = pack2h(ol[2], ol[3]);
    ulo.z = pack2h(ol[4], ol[5]); ulo.w = pack2h(ol[6], ol[7]);
    uhi.x = pack2h(oh[0], oh[1]); uhi.y = pack2h(oh[2], oh[3]);
    uhi.z = pack2h(oh[4], oh[5]); uhi.w = pack2h(oh[6], oh[7]);
    ((uint4*)dst)[c] = ulo;
    ((uint4*)dst)[c + 4] = uhi;
  }
}

// ---------------- Flash attention fwd ----------------
// grid: 64 bh * 32 q-tiles; block 256 (4 waves), QBLK=64 (16 q-rows/wave), KVBLK=128.
// K staged [128 kv][64 d] via gload_lds (slot ^= row&7); V staged [64 d][128 kv]
// via gload_lds from pre-transposed vr (slot ^= row&15). P via per-wave LDS
// (two buffers, one per 64-col half). Softmax f32, exp2 domain (scale in q).
__global__ __launch_bounds__(256) void attn_fwd(const __half* __restrict__ qr,
                                                const __half* __restrict__ kr,
                                                const __half* __restrict__ vr,
                                                __half* __restrict__ out) {
  __shared__ __half Kt[128 * 64];   // 16 KB
  __shared__ __half Vt[64 * 128];   // 16 KB
  __shared__ __half Pl[8][16 * 80]; // 20 KB (4 waves x 2 halves)

  const int bh = blockIdx.x >> 5;
  const int q0 = (blockIdx.x & 31) * 64;
  const int tid = threadIdx.x;
  const int w = tid >> 6, l = tid & 63;
  const int m16 = l & 15, g = l >> 4;
  const size_t headoff = (size_t)bh * 2048 * 64;

  // Q A-frags (rows = wave's 16 q rows), kept in registers for the whole block
  f16x8 qA[2];
  {
    const __half* qb = qr + headoff + (size_t)(q0 + w * 16 + m16) * 64 + g * 8;
    qA[0] = *(const f16x8*)qb;
    qA[1] = *(const f16x8*)(qb + 32);
  }

  // staging coords
  const int krow_l = l >> 3, kslot = l & 7;    // K: 8 rows/chunk, 8 slots/row
  const int vrow_l = l >> 4, vslot = l & 15;   // V: 4 rows/chunk, 16 slots/row
  const __half* kb = kr + headoff;
  const __half* vb = vr + (size_t)bh * 64 * 2048;

  f32x4 o[4] = {};
  float mreg[4] = {-1e30f, -1e30f, -1e30f, -1e30f};
  float lreg[4] = {0.f, 0.f, 0.f, 0.f};

  for (int kv0 = 0; kv0 < 2048; kv0 += 128) {
    __syncthreads();  // previous iteration's LDS readers done
    // ---- stage K tile [128 kv][64 d], swizzle: 16B slot ^= (row&7)
#pragma unroll
    for (int i = 0; i < 4; ++i) {
      int c = w * 4 + i;                // chunk: 1 KB = 8 rows
      int row = c * 8 + krow_l;
      gload_lds16(kb + (size_t)(kv0 + row) * 64 + ((kslot ^ (row & 7)) * 8),
                  (char*)Kt + c * 1024);
    }
    // ---- stage V tile [64 d][128 kv], swizzle: 16B slot ^= (row&15)
#pragma unroll
    for (int i = 0; i < 4; ++i) {
      int c = w * 4 + i;                // chunk: 1 KB = 4 rows
      int row = c * 4 + vrow_l;
      gload_lds16(vb + (size_t)row * 2048 + kv0 + ((vslot ^ (row & 15)) * 8),
                  (char*)Vt + c * 1024);
    }
    __syncthreads();  // vmcnt(0) drained by barrier semantics

    // ---- S = Q K^T  (16 q rows x 128 kv cols per wave)
    f32x4 s[8];
#pragma unroll
    for (int nt = 0; nt < 8; ++nt) {
      s[nt] = (f32x4){0.f, 0.f, 0.f, 0.f};
      int row = nt * 16 + m16;
#pragma unroll
      for (int kk = 0; kk < 2; ++kk) {
        int bo = row * 128 + (((kk * 4 + g) ^ (row & 7)) << 4);
        f16x8 kB = *(const f16x8*)((const char*)Kt + bo);
        s[nt] = __builtin_amdgcn_mfma_f32_16x16x32_f16(qA[kk], kB, s[nt], 0, 0, 0);
      }
    }

    // ---- online softmax (row q = g*4+j; cols spread over 8 nt + 16 lanes of group g)
    float alpha[4];
#pragma unroll
    for (int j = 0; j < 4; ++j) {
      float mt = s[0][j];
#pragma unroll
      for (int nt = 1; nt < 8; ++nt) mt = fmaxf(mt, s[nt][j]);
      mt = fmaxf(mt, __shfl_xor(mt, 1));
      mt = fmaxf(mt, __shfl_xor(mt, 2));
      mt = fmaxf(mt, __shfl_xor(mt, 4));
      mt = fmaxf(mt, __shfl_xor(mt, 8));
      float mnew = fmaxf(mreg[j], mt);
      alpha[j] = exp2f(mreg[j] - mnew);
      mreg[j] = mnew;
    }
    float rs[4] = {0.f, 0.f, 0.f, 0.f};
#pragma unroll
    for (int nt = 0; nt < 8; ++nt)
#pragma unroll
      for (int j = 0; j < 4; ++j) {
        float p = exp2f(s[nt][j] - mreg[j]);
        s[nt][j] = p;
        rs[j] += p;
      }
#pragma unroll
    for (int j = 0; j < 4; ++j) {
      rs[j] += __shfl_xor(rs[j], 1);
      rs[j] += __shfl_xor(rs[j], 2);
      rs[j] += __shfl_xor(rs[j], 4);
      rs[j] += __shfl_xor(rs[j], 8);
      lreg[j] = lreg[j] * alpha[j] + rs[j];
    }
#pragma unroll
    for (int dt = 0; dt < 4; ++dt)
#pragma unroll
      for (int j = 0; j < 4; ++j) o[dt][j] *= alpha[j];

    // ---- P -> per-wave LDS (row stride 160B, XOR swizzle), then PV; 2 halves of 64 kv
#pragma unroll
    for (int h = 0; h < 2; ++h) {
      char* pw = (char*)Pl[w * 2 + h];
#pragma unroll
      for (int nt4 = 0; nt4 < 4; ++nt4)
#pragma unroll
        for (int j = 0; j < 4; ++j) {
          int prow = g * 4 + j;
          int col = nt4 * 16 + m16;  // col within this 64-half
          int bo = prow * 160 + ((2 * col) ^ ((prow & 7) << 4));
          *(__half*)(pw + bo) = __float2half(s[h * 4 + nt4][j]);
        }
#pragma unroll
      for (int kk = 0; kk < 2; ++kk) {
        int pbo = m16 * 160 + ((kk * 64 + g * 16) ^ ((m16 & 7) << 4));
        f16x8 pA = *(const f16x8*)(pw + pbo);
#pragma unroll
        for (int dt = 0; dt < 4; ++dt) {
          int drow = dt * 16 + m16;
          int vo = drow * 256 + (((h * 8 + kk * 4 + g) ^ (drow & 15)) << 4);
          f16x8 vB = *(const f16x8*)((const char*)Vt + vo);
          o[dt] = __builtin_amdgcn_mfma_f32_16x16x32_f16(pA, vB, o[dt], 0, 0, 0);
        }
      }
    }
  }

  // ---- epilogue: normalize and store to [b][n][h*64+d]
  const int b = bh >> 4, h = bh & 15;
#pragma unroll
  for (int j = 0; j < 4; ++j) {
    float inv = 1.0f / lreg[j];
    int qrow = q0 + w * 16 + g * 4 + j;
    __half* orow = out + (size_t)(b * 2048 + qrow) * 1024 + h * 64;
#pragma unroll
    for (int dt = 0; dt < 4; ++dt)
      orow[dt * 16 + m16] = __float2half(o[dt][j] * inv);
  }
}

// ---------------- launch ----------------
extern "C" void kernel_launch(void* const* d_in, const int* in_sizes, int n_in,
                              void* d_out, int out_size, void* d_ws, size_t ws_size,
                              hipStream_t stream) {
  const float* x    = (const float*)d_in[0];  // [4,2048,1024]
  const float* rot  = (const float*)d_in[1];  // [2048,64]
  const float* wqkv = (const float*)d_in[2];  // [3072,1024]
  const float* wout = (const float*)d_in[3];  // [1024,1024]
  float* out = (float*)d_out;
  char* ws = (char*)d_ws;

  __half* xb    = (__half*)(ws + 0);               // 16 MB (dead after gemm1 -> reused as qr)
  __half* wqkvb = (__half*)(ws + (16ull << 20));   // 6 MB
  __half* woutb = (__half*)(ws + (22ull << 20));   // 2 MB
  __half* qkv   = (__half*)(ws + (24ull << 20));   // 48 MB (dead after rope -> reused as attn_out)
  __half* kr    = (__half*)(ws + (72ull << 20));   // 16 MB
  __half* vr    = (__half*)(ws + (88ull << 20));   // 16 MB (TRANSPOSED [bh][d][n]); total 104 MB
  __half* qr    = xb;
  __half* ao    = qkv;

  cvt_f32_f16<<<4096, 256, 0, stream>>>(x, xb, 1048576);
  cvt_f32_f16<<<1536, 256, 0, stream>>>(wqkv, wqkvb, 393216);
  cvt_f32_f16<<<512, 256, 0, stream>>>(wout, woutb, 131072);
  // qkv = xb @ wqkvb^T   [8192,3072]
  gemm_bt<__half><<<dim3(24, 64), 256, 0, stream>>>(xb, wqkvb, qkv, 8192, 3072, 1024);
  rope_scatter<<<1536, 256, 0, stream>>>(qkv, rot, qr, kr, vr);
  attn_fwd<<<2048, 256, 0, stream>>>(qr, kr, vr, ao);
  // out = ao @ woutb^T   [8192,1024] f32
  gemm_bt<float><<<dim3(8, 64), 256, 0, stream>>>(ao, woutb, out, 8192, 1024, 1024);
}

// Round 4
// 297.829 us; speedup vs baseline: 1.3747x; 1.2212x over previous
//
#include <hip/hip_runtime.h>
#include <hip/hip_fp16.h>
#include <stdint.h>

#define DEVI __device__ __forceinline__

using f16x8 = __attribute__((ext_vector_type(8))) _Float16;
using f32x4 = __attribute__((ext_vector_type(4))) float;
using f32x16 = __attribute__((ext_vector_type(16))) float;
using u32x4 = __attribute__((ext_vector_type(4))) uint32_t;

// global -> LDS direct copy, 16B per lane. LDS dest is wave-uniform base;
// HW writes base + lane*16 (guide m104/m108). Global src is per-lane.
DEVI void gload_lds16(const void* g, void* lds) {
  using GP = const __attribute__((address_space(1))) void*;
  using LP = __attribute__((address_space(3))) void*;
  __builtin_amdgcn_global_load_lds((GP)g, (LP)lds, 16, 0, 0);
}

DEVI uint32_t pack2h(float a, float b) {
  return (uint32_t)__half_as_ushort(__float2half(a)) |
         ((uint32_t)__half_as_ushort(__float2half(b)) << 16);
}

DEVI uint32_t cvtpk(float a, float b) {  // v_cvt_pkrtz_f16_f32
  auto h2 = __builtin_amdgcn_cvt_pkrtz(a, b);
  return __builtin_bit_cast(uint32_t, h2);
}

// ---------------- f32 -> f16 convert (vectorized, G13) ----------------
__global__ __launch_bounds__(256) void cvt_f32_f16(const float* __restrict__ in,
                                                   __half* __restrict__ out, int n8) {
  int i = blockIdx.x * 256 + threadIdx.x;
  if (i >= n8) return;
  float4 a = ((const float4*)in)[i * 2];
  float4 b = ((const float4*)in)[i * 2 + 1];
  uint4 u;
  u.x = pack2h(a.x, a.y);
  u.y = pack2h(a.z, a.w);
  u.z = pack2h(b.x, b.y);
  u.w = pack2h(b.z, b.w);
  ((uint4*)out)[i] = u;
}

// ---------------- GEMM: C[M][N] = A[M][K] * B[N][K]^T, f16 in, f32 acc ----------------
// 128x128 tile, BK=32, 4 waves (2x2), 16x16x32 f16 MFMA. (unchanged)
DEVI void store_c(__half* p, float v) { *p = __float2half(v); }
DEVI void store_c(float* p, float v) { *p = v; }

template <typename OT>
__global__ __launch_bounds__(256) void gemm_bt(const __half* __restrict__ A,
                                               const __half* __restrict__ B,
                                               OT* __restrict__ C, int M, int N, int K) {
  __shared__ __half As[128 * 32];
  __shared__ __half Bs[128 * 32];
  const int tid = threadIdx.x;
  const int w = tid >> 6, l = tid & 63;
  const int wm = w >> 1, wn = w & 1;
  const int m16 = l & 15, g = l >> 4;
  const int row0 = blockIdx.y * 128, col0 = blockIdx.x * 128;

  const int srow = l >> 2;
  const int ks = ((l & 3) ^ (srow & 3)) * 8;  // f16 elements

  f32x4 acc[4][4] = {};

  for (int kt = 0; kt < K; kt += 32) {
    __syncthreads();
#pragma unroll
    for (int i = 0; i < 2; ++i) {
      int c = w * 2 + i;
      int r = c * 16 + srow;
      gload_lds16(A + (size_t)(row0 + r) * K + kt + ks, (char*)As + c * 1024);
      gload_lds16(B + (size_t)(col0 + r) * K + kt + ks, (char*)Bs + c * 1024);
    }
    __syncthreads();
    f16x8 aF[4], bF[4];
#pragma unroll
    for (int mi = 0; mi < 4; ++mi) {
      int r = wm * 64 + mi * 16 + m16;
      aF[mi] = *(const f16x8*)((const char*)As + r * 64 + ((g << 4) ^ ((r & 3) << 4)));
    }
#pragma unroll
    for (int ni = 0; ni < 4; ++ni) {
      int r = wn * 64 + ni * 16 + m16;
      bF[ni] = *(const f16x8*)((const char*)Bs + r * 64 + ((g << 4) ^ ((r & 3) << 4)));
    }
#pragma unroll
    for (int mi = 0; mi < 4; ++mi)
#pragma unroll
      for (int ni = 0; ni < 4; ++ni)
        acc[mi][ni] = __builtin_amdgcn_mfma_f32_16x16x32_f16(aF[mi], bF[ni], acc[mi][ni], 0, 0, 0);
  }

#pragma unroll
  for (int mi = 0; mi < 4; ++mi)
#pragma unroll
    for (int ni = 0; ni < 4; ++ni)
#pragma unroll
      for (int j = 0; j < 4; ++j) {
        int r = row0 + wm * 64 + mi * 16 + g * 4 + j;
        int cc = col0 + wn * 64 + ni * 16 + m16;
        store_c(&C[(size_t)r * N + cc], acc[mi][ni][j]);
      }
}

// ---------------- RoPE + scatter to per-head layout ----------------
// qkv: [8192][3072] f16 (row = b*2048+n, col = s*1024 + h*64 + d)
// outputs: qr/kr [64 bh][2048 n][64 d]; vr TRANSPOSED [64 bh][64 d][2048 n].
// q pre-scaled by log2(e)/8 so attn uses exp2 with no per-element scale.
__global__ __launch_bounds__(256) void rope_scatter(const __half* __restrict__ qkv,
                                                    const float* __restrict__ rot,
                                                    __half* __restrict__ qr,
                                                    __half* __restrict__ kr,
                                                    __half* __restrict__ vr) {
  int t = blockIdx.x * 256 + threadIdx.x;  // 3*64*2048 threads
  int s = t >> 17;
  int rem = t & 131071;
  int bh = rem >> 11;
  int n = rem & 2047;
  int b = bh >> 4, h = bh & 15;
  const __half* src = qkv + (size_t)(b * 2048 + n) * 3072 + s * 1024 + h * 64;
  if (s == 2) {
    // transposed store: vr[bh][d][n]; scalar stores, coalesced across lanes
    __half* vdst = vr + ((size_t)bh * 64) * 2048 + n;
#pragma unroll
    for (int c = 0; c < 8; ++c) {
      f16x8 vv = ((const f16x8*)src)[c];
#pragma unroll
      for (int j = 0; j < 8; ++j) vdst[(size_t)(c * 8 + j) * 2048] = vv[j];
    }
    return;
  }
  __half* dst = (s == 0 ? qr : kr) + ((size_t)bh * 2048 + n) * 64;
  const float sc = (s == 0) ? 0.18033688011112042f : 1.0f;  // log2(e)/sqrt(64)
  const float* rp = rot + n * 64;
#pragma unroll
  for (int c = 0; c < 4; ++c) {
    f16x8 lo = ((const f16x8*)src)[c];      // d = 8c .. 8c+7
    f16x8 hi = ((const f16x8*)src)[c + 4];  // d+32
    float ol[8], oh[8];
#pragma unroll
    for (int j = 0; j < 8; ++j) {
      int d = c * 8 + j;
      float tl = (float)lo[j], th = (float)hi[j];
      float s0, c0, s1, c1;
      __sincosf(rp[d], &s0, &c0);
      __sincosf(rp[d + 32], &s1, &c1);
      ol[j] = (tl * c0 - th * s0) * sc;
      oh[j] = (th * c1 + tl * s1) * sc;
    }
    uint4 ulo, uhi;
    ulo.x = pack2h(ol[0], ol[1]); ulo.y = pack2h(ol[2], ol[3]);
    ulo.z = pack2h(ol[4], ol[5]); ulo.w = pack2h(ol[6], ol[7]);
    uhi.x = pack2h(oh[0], oh[1]); uhi.y = pack2h(oh[2], oh[3]);
    uhi.z = pack2h(oh[4], oh[5]); uhi.w = pack2h(oh[6], oh[7]);
    ((uint4*)dst)[c] = ulo;
    ((uint4*)dst)[c + 4] = uhi;
  }
}

// ---------------- Flash attention fwd, swapped-QK 32x32 (T12/T13) ----------------
// grid: 64 bh * 16 q-tiles (128 q rows/block); block 256 = 4 warps, 32 q rows/warp.
// S^T = mfma32(K, Q): lane owns ONE q-col (l&31), 16 kv scores in acc regs
// (kv row of reg r = (r&3)+8*(r>>2)+4*(l>>5)). Softmax fully in-register:
// 15 fmax + 1 shfl_xor(32); P -> PV A-frags via 8 cvt_pkrtz + 8 shfl + 8 sel.
// V read as B-frag from pre-transposed Vt[d][kv]. Defer-max THR=8 (T13).
__global__ __launch_bounds__(256) void attn_fwd(const __half* __restrict__ qr,
                                                const __half* __restrict__ kr,
                                                const __half* __restrict__ vr,
                                                __half* __restrict__ out) {
  __shared__ __half Kt[128 * 64];   // [kv][d] 16 KB, 16B slot ^= kv&7
  __shared__ __half Vt[64 * 128];   // [d][kv] 16 KB, 16B slot ^= d&15

  const int bh = blockIdx.x >> 4;
  const int q0 = (blockIdx.x & 15) * 128;
  const int tid = threadIdx.x;
  const int w = tid >> 6, l = tid & 63;
  const int q = l & 31, hi = l >> 5;
  const size_t headoff = (size_t)bh * 2048 * 64;

  // Q B-frags: Q[q0+w*32+q][c*16 + hi*8 .. +7], c=0..3 (held all block)
  f16x8 qB[4];
  {
    const __half* qp = qr + headoff + (size_t)(q0 + w * 32 + q) * 64 + hi * 8;
#pragma unroll
    for (int c = 0; c < 4; ++c) qB[c] = *(const f16x8*)(qp + c * 16);
  }

  // staging coords (identical scheme to round 3)
  const int krow_l = l >> 3, kslot = l & 7;    // K: 8 rows/1KB chunk
  const int vrow_l = l >> 4, vslot = l & 15;   // V: 4 rows/1KB chunk
  const __half* kb = kr + headoff;
  const __half* vb = vr + (size_t)bh * 64 * 2048;

  f32x16 o0 = {}, o1 = {};                 // O[q-rows][d 0-31 / 32-63], col = d = q(lane)
  float mreg = -1e30f, lreg = 0.f;

  for (int kv0 = 0; kv0 < 2048; kv0 += 128) {
    __syncthreads();
#pragma unroll
    for (int i = 0; i < 4; ++i) {          // K tile [128 kv][64 d]
      int c = w * 4 + i;
      int row = c * 8 + krow_l;
      gload_lds16(kb + (size_t)(kv0 + row) * 64 + ((kslot ^ (row & 7)) * 8),
                  (char*)Kt + c * 1024);
    }
#pragma unroll
    for (int i = 0; i < 4; ++i) {          // V tile [64 d][128 kv]
      int c = w * 4 + i;
      int row = c * 4 + vrow_l;
      gload_lds16(vb + (size_t)row * 2048 + kv0 + ((vslot ^ (row & 15)) * 8),
                  (char*)Vt + c * 1024);
    }
    __syncthreads();

#pragma unroll
    for (int kvb = 0; kvb < 128; kvb += 32) {
      // ---- S^T[kv 32][q 32] = K_tile * Q^T
      f32x16 s = {};
      const int kvr = kvb + q;             // A-frag row (kv) for this lane
      const int kbase = kvr * 128;
      const int ksw = (kvr & 7) << 4;
#pragma unroll
      for (int c = 0; c < 4; ++c) {
        f16x8 kA = *(const f16x8*)((const char*)Kt + kbase + ((c * 32 + hi * 16) ^ ksw));
        s = __builtin_amdgcn_mfma_f32_32x32x16_f16(kA, qB[c], s, 0, 0, 0);
      }

      // ---- in-register online softmax for q-col (l&31)
      float mt = s[0];
#pragma unroll
      for (int r = 1; r < 16; ++r) mt = fmaxf(mt, s[r]);
      mt = fmaxf(mt, __shfl_xor(mt, 32));
      if (__any(mt > mreg + 8.f)) {        // defer-max (T13)
        float mnew = fmaxf(mreg, mt);
        float alpha = exp2f(mreg - mnew);
        lreg *= alpha;
        o0 *= alpha;
        o1 *= alpha;
        mreg = mnew;
      }
      float p[16];
      float rs = 0.f;
#pragma unroll
      for (int r = 0; r < 16; ++r) {
        p[r] = exp2f(s[r] - mreg);
        rs += p[r];
      }
      rs += __shfl_xor(rs, 32);
      lreg += rs;

      // ---- P (f32, kv rows per-lane) -> f16 PV A-frags, in registers
      uint32_t W[8], X[8];
#pragma unroll
      for (int i = 0; i < 8; ++i) W[i] = cvtpk(p[2 * i], p[2 * i + 1]);
#pragma unroll
      for (int i = 0; i < 8; ++i) X[i] = __shfl_xor((int)W[i], 32);
      u32x4 f0, f1;
      f0[0] = hi ? X[2] : W[0]; f0[1] = hi ? X[3] : W[1];
      f0[2] = hi ? W[2] : X[0]; f0[3] = hi ? W[3] : X[1];
      f1[0] = hi ? X[6] : W[4]; f1[1] = hi ? X[7] : W[5];
      f1[2] = hi ? W[6] : X[4]; f1[3] = hi ? W[7] : X[5];
      f16x8 pA0 = __builtin_bit_cast(f16x8, f0);   // kv block kvb+0..15
      f16x8 pA1 = __builtin_bit_cast(f16x8, f1);   // kv block kvb+16..31

      // ---- PV: O[32q][64d] += P * V  (V B-frag from Vt[d][kv], contiguous)
      const int d0 = q, d1 = 32 + q;
      const int sw0 = (d0 & 15) << 4, sw1 = (d1 & 15) << 4;
      {
        int ko = (kvb + hi * 8) * 2;
        f16x8 v00 = *(const f16x8*)((const char*)Vt + d0 * 256 + (ko ^ sw0));
        f16x8 v01 = *(const f16x8*)((const char*)Vt + d1 * 256 + (ko ^ sw1));
        o0 = __builtin_amdgcn_mfma_f32_32x32x16_f16(pA0, v00, o0, 0, 0, 0);
        o1 = __builtin_amdgcn_mfma_f32_32x32x16_f16(pA0, v01, o1, 0, 0, 0);
      }
      {
        int ko = (kvb + 16 + hi * 8) * 2;
        f16x8 v10 = *(const f16x8*)((const char*)Vt + d0 * 256 + (ko ^ sw0));
        f16x8 v11 = *(const f16x8*)((const char*)Vt + d1 * 256 + (ko ^ sw1));
        o0 = __builtin_amdgcn_mfma_f32_32x32x16_f16(pA1, v10, o0, 0, 0, 0);
        o1 = __builtin_amdgcn_mfma_f32_32x32x16_f16(pA1, v11, o1, 0, 0, 0);
      }
    }
  }

  // ---- epilogue: O reg r holds q-row (r&3)+8*(r>>2)+4*hi, d-col q (+0/32)
  const int b = bh >> 4, hh = bh & 15;
  float invl = 1.0f / lreg;                // for q-col (l&31); redistribute via shfl
#pragma unroll
  for (int r = 0; r < 16; ++r) {
    int qrow = (r & 3) + 8 * (r >> 2) + 4 * hi;
    float inv = __shfl(invl, qrow);        // lane qrow (hi=0) owns that q-row's l
    __half* orow = out + (size_t)(b * 2048 + q0 + w * 32 + qrow) * 1024 + hh * 64;
    orow[q] = __float2half(o0[r] * inv);
    orow[32 + q] = __float2half(o1[r] * inv);
  }
}

// ---------------- launch ----------------
extern "C" void kernel_launch(void* const* d_in, const int* in_sizes, int n_in,
                              void* d_out, int out_size, void* d_ws, size_t ws_size,
                              hipStream_t stream) {
  const float* x    = (const float*)d_in[0];  // [4,2048,1024]
  const float* rot  = (const float*)d_in[1];  // [2048,64]
  const float* wqkv = (const float*)d_in[2];  // [3072,1024]
  const float* wout = (const float*)d_in[3];  // [1024,1024]
  float* out = (float*)d_out;
  char* ws = (char*)d_ws;

  __half* xb    = (__half*)(ws + 0);               // 16 MB (reused as qr)
  __half* wqkvb = (__half*)(ws + (16ull << 20));   // 6 MB
  __half* woutb = (__half*)(ws + (22ull << 20));   // 2 MB
  __half* qkv   = (__half*)(ws + (24ull << 20));   // 48 MB (reused as attn_out)
  __half* kr    = (__half*)(ws + (72ull << 20));   // 16 MB
  __half* vr    = (__half*)(ws + (88ull << 20));   // 16 MB (TRANSPOSED [bh][d][n])
  __half* qr    = xb;
  __half* ao    = qkv;

  cvt_f32_f16<<<4096, 256, 0, stream>>>(x, xb, 1048576);
  cvt_f32_f16<<<1536, 256, 0, stream>>>(wqkv, wqkvb, 393216);
  cvt_f32_f16<<<512, 256, 0, stream>>>(wout, woutb, 131072);
  // qkv = xb @ wqkvb^T   [8192,3072]
  gemm_bt<__half><<<dim3(24, 64), 256, 0, stream>>>(xb, wqkvb, qkv, 8192, 3072, 1024);
  rope_scatter<<<1536, 256, 0, stream>>>(qkv, rot, qr, kr, vr);
  attn_fwd<<<1024, 256, 0, stream>>>(qr, kr, vr, ao);
  // out = ao @ woutb^T   [8192,1024] f32
  gemm_bt<float><<<dim3(8, 64), 256, 0, stream>>>(ao, woutb, out, 8192, 1024, 1024);
}

// Round 5
// 270.561 us; speedup vs baseline: 1.5132x; 1.1008x over previous
//
#include <hip/hip_runtime.h>
#include <hip/hip_fp16.h>
#include <stdint.h>

#define DEVI __device__ __forceinline__

using f16x2 = __attribute__((ext_vector_type(2))) _Float16;
using f16x8 = __attribute__((ext_vector_type(8))) _Float16;
using f32x4 = __attribute__((ext_vector_type(4))) float;
using f32x16 = __attribute__((ext_vector_type(16))) float;
using u32x4 = __attribute__((ext_vector_type(4))) uint32_t;

// global -> LDS direct copy, 16B per lane. LDS dest is wave-uniform base;
// HW writes base + lane*16 (guide m104/m108). Global src is per-lane.
DEVI void gload_lds16(const void* g, void* lds) {
  using GP = const __attribute__((address_space(1))) void*;
  using LP = __attribute__((address_space(3))) void*;
  __builtin_amdgcn_global_load_lds((GP)g, (LP)lds, 16, 0, 0);
}

DEVI uint32_t pack2h(float a, float b) {
  return (uint32_t)__half_as_ushort(__float2half(a)) |
         ((uint32_t)__half_as_ushort(__float2half(b)) << 16);
}

DEVI uint32_t cvtpk(float a, float b) {  // v_cvt_pkrtz_f16_f32
  auto h2 = __builtin_amdgcn_cvt_pkrtz(a, b);
  return __builtin_bit_cast(uint32_t, h2);
}

DEVI void plswap(uint32_t& a, uint32_t& b) {  // v_permlane32_swap_b32
  asm volatile("v_permlane32_swap_b32 %0, %1" : "+v"(a), "+v"(b));
}

DEVI float dot2acc(uint32_t w, f16x2 one, float c) {  // v_dot2_f32_f16
  return __builtin_amdgcn_fdot2(__builtin_bit_cast(f16x2, w), one, c, false);
}

DEVI float fmax3(float a, float b, float c) { return fmaxf(fmaxf(a, b), c); }

// ---------------- f32 -> f16 convert (vectorized, G13) ----------------
__global__ __launch_bounds__(256) void cvt_f32_f16(const float* __restrict__ in,
                                                   __half* __restrict__ out, int n8) {
  int i = blockIdx.x * 256 + threadIdx.x;
  if (i >= n8) return;
  float4 a = ((const float4*)in)[i * 2];
  float4 b = ((const float4*)in)[i * 2 + 1];
  uint4 u;
  u.x = pack2h(a.x, a.y);
  u.y = pack2h(a.z, a.w);
  u.z = pack2h(b.x, b.y);
  u.w = pack2h(b.z, b.w);
  ((uint4*)out)[i] = u;
}

// ---------------- GEMM: C[M][N] = A[M][K] * B[N][K]^T, f16 in, f32 acc ----------------
// 128x128 tile, BK=32, 4 waves (2x2), 16x16x32 f16 MFMA. (unchanged)
DEVI void store_c(__half* p, float v) { *p = __float2half(v); }
DEVI void store_c(float* p, float v) { *p = v; }

template <typename OT>
__global__ __launch_bounds__(256) void gemm_bt(const __half* __restrict__ A,
                                               const __half* __restrict__ B,
                                               OT* __restrict__ C, int M, int N, int K) {
  __shared__ __half As[128 * 32];
  __shared__ __half Bs[128 * 32];
  const int tid = threadIdx.x;
  const int w = tid >> 6, l = tid & 63;
  const int wm = w >> 1, wn = w & 1;
  const int m16 = l & 15, g = l >> 4;
  const int row0 = blockIdx.y * 128, col0 = blockIdx.x * 128;

  const int srow = l >> 2;
  const int ks = ((l & 3) ^ (srow & 3)) * 8;  // f16 elements

  f32x4 acc[4][4] = {};

  for (int kt = 0; kt < K; kt += 32) {
    __syncthreads();
#pragma unroll
    for (int i = 0; i < 2; ++i) {
      int c = w * 2 + i;
      int r = c * 16 + srow;
      gload_lds16(A + (size_t)(row0 + r) * K + kt + ks, (char*)As + c * 1024);
      gload_lds16(B + (size_t)(col0 + r) * K + kt + ks, (char*)Bs + c * 1024);
    }
    __syncthreads();
    f16x8 aF[4], bF[4];
#pragma unroll
    for (int mi = 0; mi < 4; ++mi) {
      int r = wm * 64 + mi * 16 + m16;
      aF[mi] = *(const f16x8*)((const char*)As + r * 64 + ((g << 4) ^ ((r & 3) << 4)));
    }
#pragma unroll
    for (int ni = 0; ni < 4; ++ni) {
      int r = wn * 64 + ni * 16 + m16;
      bF[ni] = *(const f16x8*)((const char*)Bs + r * 64 + ((g << 4) ^ ((r & 3) << 4)));
    }
#pragma unroll
    for (int mi = 0; mi < 4; ++mi)
#pragma unroll
      for (int ni = 0; ni < 4; ++ni)
        acc[mi][ni] = __builtin_amdgcn_mfma_f32_16x16x32_f16(aF[mi], bF[ni], acc[mi][ni], 0, 0, 0);
  }

#pragma unroll
  for (int mi = 0; mi < 4; ++mi)
#pragma unroll
    for (int ni = 0; ni < 4; ++ni)
#pragma unroll
      for (int j = 0; j < 4; ++j) {
        int r = row0 + wm * 64 + mi * 16 + g * 4 + j;
        int cc = col0 + wn * 64 + ni * 16 + m16;
        store_c(&C[(size_t)r * N + cc], acc[mi][ni][j]);
      }
}

// ---------------- RoPE + scatter to per-head layout ----------------
// qkv: [8192][3072] f16 (row = b*2048+n, col = s*1024 + h*64 + d)
// outputs: qr/kr [64 bh][2048 n][64 d]; vr TRANSPOSED [64 bh][64 d][2048 n].
// q pre-scaled by log2(e)/8 so attn uses exp2 with no per-element scale.
__global__ __launch_bounds__(256) void rope_scatter(const __half* __restrict__ qkv,
                                                    const float* __restrict__ rot,
                                                    __half* __restrict__ qr,
                                                    __half* __restrict__ kr,
                                                    __half* __restrict__ vr) {
  int t = blockIdx.x * 256 + threadIdx.x;  // 3*64*2048 threads
  int s = t >> 17;
  int rem = t & 131071;
  int bh = rem >> 11;
  int n = rem & 2047;
  int b = bh >> 4, h = bh & 15;
  const __half* src = qkv + (size_t)(b * 2048 + n) * 3072 + s * 1024 + h * 64;
  if (s == 2) {
    // transposed store: vr[bh][d][n]; scalar stores, coalesced across lanes
    __half* vdst = vr + ((size_t)bh * 64) * 2048 + n;
#pragma unroll
    for (int c = 0; c < 8; ++c) {
      f16x8 vv = ((const f16x8*)src)[c];
#pragma unroll
      for (int j = 0; j < 8; ++j) vdst[(size_t)(c * 8 + j) * 2048] = vv[j];
    }
    return;
  }
  __half* dst = (s == 0 ? qr : kr) + ((size_t)bh * 2048 + n) * 64;
  const float sc = (s == 0) ? 0.18033688011112042f : 1.0f;  // log2(e)/sqrt(64)
  const float* rp = rot + n * 64;
#pragma unroll
  for (int c = 0; c < 4; ++c) {
    f16x8 lo = ((const f16x8*)src)[c];      // d = 8c .. 8c+7
    f16x8 hi = ((const f16x8*)src)[c + 4];  // d+32
    float ol[8], oh[8];
#pragma unroll
    for (int j = 0; j < 8; ++j) {
      int d = c * 8 + j;
      float tl = (float)lo[j], th = (float)hi[j];
      float s0, c0, s1, c1;
      __sincosf(rp[d], &s0, &c0);
      __sincosf(rp[d + 32], &s1, &c1);
      ol[j] = (tl * c0 - th * s0) * sc;
      oh[j] = (th * c1 + tl * s1) * sc;
    }
    uint4 ulo, uhi;
    ulo.x = pack2h(ol[0], ol[1]); ulo.y = pack2h(ol[2], ol[3]);
    ulo.z = pack2h(ol[4], ol[5]); ulo.w = pack2h(ol[6], ol[7]);
    uhi.x = pack2h(oh[0], oh[1]); uhi.y = pack2h(oh[2], oh[3]);
    uhi.z = pack2h(oh[4], oh[5]); uhi.w = pack2h(oh[6], oh[7]);
    ((uint4*)dst)[c] = ulo;
    ((uint4*)dst)[c + 4] = uhi;
  }
}

// ---------------- Flash attention fwd, swapped-QK 32x32, 2-phase pipeline ----------------
// grid 1024 (XCD-swizzled): 64 bh * 16 q-tiles; block 256 = 4 waves, 32 q rows/wave.
// Double-buffered K/V LDS (64 KB); per tile: STAGE(next) || compute(cur); one
// raw s_barrier + explicit vmcnt(0) per tile (T3 2-phase recipe).
// K tile [128 kv][64 d], 16B slot ^= kv&7 (additive-invariant: (kvb+q)&7==q&7).
// V tile [4 kvb][64 d][64B], 16B slot ^= d&3 (kvb additive => ds_read imm).
// Softmax in-register (T12): max3 tree + exp2 + cvt_pkrtz + fdot2 row-sum +
// permlane32_swap A-frag redistribution. Defer-max THR=8 (T13). setprio (T5).
__global__ __launch_bounds__(256, 2) void attn_fwd(const __half* __restrict__ qr,
                                                   const __half* __restrict__ kr,
                                                   const __half* __restrict__ vr,
                                                   __half* __restrict__ out) {
  __shared__ __half K2[2 * 128 * 64];  // 32 KB
  __shared__ __half V2[2 * 64 * 128];  // 32 KB

  int bid = blockIdx.x;
  bid = (bid & 7) * 128 + (bid >> 3);  // XCD swizzle: same-head blocks share an XCD L2
  const int bh = bid >> 4;
  const int q0 = (bid & 15) * 128;
  const int tid = threadIdx.x;
  const int w = tid >> 6, l = tid & 63;
  const int q = l & 31, hi = l >> 5;
  const size_t headoff = (size_t)bh * 2048 * 64;

  // Q B-frags: Q[q0+w*32+q][c*16 + hi*8 .. +7], c=0..3 (held all block)
  f16x8 qB[4];
  {
    const __half* qp = qr + headoff + (size_t)(q0 + w * 32 + q) * 64 + hi * 8;
#pragma unroll
    for (int c = 0; c < 4; ++c) qB[c] = *(const f16x8*)(qp + c * 16);
  }

  // hoisted lane-invariant LDS read offsets
  int kf[4];  // K A-frag: byte = buf + kvb*4096 + kf[c]
#pragma unroll
  for (int c = 0; c < 4; ++c)
    kf[c] = q * 128 + 16 * (hi ^ (q & 1)) + 32 * (c ^ ((q >> 1) & 3));
  const int vb00 = q * 64 + 16 * (hi ^ (q & 1)) + 32 * ((q >> 1) & 1);        // d0, kv half 0
  const int vb01 = q * 64 + 16 * (hi ^ (q & 1)) + 32 * (1 ^ ((q >> 1) & 1));  // d0, kv half 1

  // staging coords
  const int krow_l = l >> 3, kslot = l & 7;  // K: 8 rows per 1KB chunk
  const __half* kb = kr + headoff;
  const __half* vb = vr + (size_t)bh * 64 * 2048;

  auto STAGE = [&](int buf, int kv0) {
#pragma unroll
    for (int i = 0; i < 4; ++i) {  // K [128][64]
      int c = w * 4 + i;
      int row = c * 8 + krow_l;
      gload_lds16(kb + (size_t)(kv0 + row) * 64 + ((kslot ^ (row & 7)) * 8),
                  (char*)K2 + buf * 16384 + c * 1024);
    }
#pragma unroll
    for (int i = 0; i < 4; ++i) {  // V [4 kvb][64 d][64B]; wave w stages kvb=w
      int c = w * 4 + i;
      int d = i * 16 + (l >> 2);
      gload_lds16(vb + (size_t)d * 2048 + kv0 + w * 32 + (((l & 3) ^ (d & 3)) * 8),
                  (char*)V2 + buf * 16384 + c * 1024);
    }
  };

  const f16x2 one2 = {(_Float16)1.f, (_Float16)1.f};
  f32x16 o0 = {}, o1 = {};  // O[q-rows][d0=q / d1=q+32]
  float mreg = -1e30f, lreg = 0.f;

  // prologue: stage tile 0, drain, barrier
  STAGE(0, 0);
  asm volatile("s_waitcnt vmcnt(0)" ::: "memory");
  __builtin_amdgcn_s_barrier();

  for (int t = 0; t < 16; ++t) {
    const int buf = t & 1;
    if (t < 15) STAGE(buf ^ 1, (t + 1) * 128);  // prefetch next tile (overlaps compute)

    const char* Kb = (const char*)K2 + buf * 16384;
    const char* Vb = (const char*)V2 + buf * 16384;
#pragma unroll
    for (int kvb = 0; kvb < 4; ++kvb) {
      // ---- S^T[kv 32][q 32] = K * Q^T
      f32x16 s = {};
      __builtin_amdgcn_s_setprio(1);
#pragma unroll
      for (int c = 0; c < 4; ++c) {
        f16x8 kA = *(const f16x8*)(Kb + kvb * 4096 + kf[c]);
        s = __builtin_amdgcn_mfma_f32_32x32x16_f16(kA, qB[c], s, 0, 0, 0);
      }
      __builtin_amdgcn_s_setprio(0);

      // ---- in-register online softmax (lane owns q-col l&31, 16 kv rows)
      float mt = fmax3(s[0], s[1], s[2]);
      mt = fmax3(mt, s[3], s[4]);
      mt = fmax3(mt, s[5], s[6]);
      mt = fmax3(mt, s[7], s[8]);
      mt = fmax3(mt, s[9], s[10]);
      mt = fmax3(mt, s[11], s[12]);
      mt = fmax3(mt, s[13], s[14]);
      mt = fmaxf(mt, s[15]);
      mt = fmaxf(mt, __shfl_xor(mt, 32));
      if (__any(mt - mreg > 8.f)) {  // defer-max (T13)
        float mnew = fmaxf(mreg, mt);
        float alpha = __builtin_amdgcn_exp2f(mreg - mnew);
        lreg *= alpha;
        o0 *= alpha;
        o1 *= alpha;
        mreg = mnew;
      }
      uint32_t W[8];
      float rs = 0.f;
#pragma unroll
      for (int i2 = 0; i2 < 8; ++i2) {  // exp2 + pack + fused row-sum (fdot2)
        float e0 = __builtin_amdgcn_exp2f(s[2 * i2] - mreg);
        float e1 = __builtin_amdgcn_exp2f(s[2 * i2 + 1] - mreg);
        W[i2] = cvtpk(e0, e1);
        rs = dot2acc(W[i2], one2, rs);
      }
      rs += __shfl_xor(rs, 32);
      lreg += rs;

      // ---- P-frag redistribution: 4 permlane32_swap (replaces 8 shfl + 16 sel)
      plswap(W[0], W[2]);
      plswap(W[1], W[3]);
      plswap(W[4], W[6]);
      plswap(W[5], W[7]);
      u32x4 f0 = {W[0], W[1], W[2], W[3]};
      u32x4 f1 = {W[4], W[5], W[6], W[7]};
      f16x8 pA0 = __builtin_bit_cast(f16x8, f0);  // kv kvb*32 + 0..15
      f16x8 pA1 = __builtin_bit_cast(f16x8, f1);  // kv kvb*32 + 16..31

      // ---- PV: O += P * V  (V B-frags, kvb folds into ds_read immediates)
      const char* Vk = Vb + kvb * 4096;
      f16x8 v00 = *(const f16x8*)(Vk + vb00);
      f16x8 v01 = *(const f16x8*)(Vk + vb00 + 2048);
      f16x8 v10 = *(const f16x8*)(Vk + vb01);
      f16x8 v11 = *(const f16x8*)(Vk + vb01 + 2048);
      __builtin_amdgcn_s_setprio(1);
      o0 = __builtin_amdgcn_mfma_f32_32x32x16_f16(pA0, v00, o0, 0, 0, 0);
      o1 = __builtin_amdgcn_mfma_f32_32x32x16_f16(pA0, v01, o1, 0, 0, 0);
      o0 = __builtin_amdgcn_mfma_f32_32x32x16_f16(pA1, v10, o0, 0, 0, 0);
      o1 = __builtin_amdgcn_mfma_f32_32x32x16_f16(pA1, v11, o1, 0, 0, 0);
      __builtin_amdgcn_s_setprio(0);
    }

    asm volatile("s_waitcnt vmcnt(0)" ::: "memory");  // next tile fully in LDS
    __builtin_amdgcn_s_barrier();
  }

  // ---- epilogue: O reg r holds q-row (r&3)+8*(r>>2)+4*hi, d-col q (+0/32)
  const int b = bh >> 4, hh = bh & 15;
  float invl = 1.0f / lreg;
#pragma unroll
  for (int r = 0; r < 16; ++r) {
    int qrow = (r & 3) + 8 * (r >> 2) + 4 * hi;
    float inv = __shfl(invl, qrow);
    __half* orow = out + (size_t)(b * 2048 + q0 + w * 32 + qrow) * 1024 + hh * 64;
    orow[q] = __float2half(o0[r] * inv);
    orow[32 + q] = __float2half(o1[r] * inv);
  }
}

// ---------------- launch ----------------
extern "C" void kernel_launch(void* const* d_in, const int* in_sizes, int n_in,
                              void* d_out, int out_size, void* d_ws, size_t ws_size,
                              hipStream_t stream) {
  const float* x    = (const float*)d_in[0];  // [4,2048,1024]
  const float* rot  = (const float*)d_in[1];  // [2048,64]
  const float* wqkv = (const float*)d_in[2];  // [3072,1024]
  const float* wout = (const float*)d_in[3];  // [1024,1024]
  float* out = (float*)d_out;
  char* ws = (char*)d_ws;

  __half* xb    = (__half*)(ws + 0);               // 16 MB (reused as qr)
  __half* wqkvb = (__half*)(ws + (16ull << 20));   // 6 MB
  __half* woutb = (__half*)(ws + (22ull << 20));   // 2 MB
  __half* qkv   = (__half*)(ws + (24ull << 20));   // 48 MB (reused as attn_out)
  __half* kr    = (__half*)(ws + (72ull << 20));   // 16 MB
  __half* vr    = (__half*)(ws + (88ull << 20));   // 16 MB (TRANSPOSED [bh][d][n])
  __half* qr    = xb;
  __half* ao    = qkv;

  cvt_f32_f16<<<4096, 256, 0, stream>>>(x, xb, 1048576);
  cvt_f32_f16<<<1536, 256, 0, stream>>>(wqkv, wqkvb, 393216);
  cvt_f32_f16<<<512, 256, 0, stream>>>(wout, woutb, 131072);
  // qkv = xb @ wqkvb^T   [8192,3072]
  gemm_bt<__half><<<dim3(24, 64), 256, 0, stream>>>(xb, wqkvb, qkv, 8192, 3072, 1024);
  rope_scatter<<<1536, 256, 0, stream>>>(qkv, rot, qr, kr, vr);
  attn_fwd<<<1024, 256, 0, stream>>>(qr, kr, vr, ao);
  // out = ao @ woutb^T   [8192,1024] f32
  gemm_bt<float><<<dim3(8, 64), 256, 0, stream>>>(ao, woutb, out, 8192, 1024, 1024);
}

// Round 8
// 267.014 us; speedup vs baseline: 1.5333x; 1.0133x over previous
//
#include <hip/hip_runtime.h>
#include <hip/hip_fp16.h>
#include <stdint.h>

#define DEVI __device__ __forceinline__

using f16x2 = __attribute__((ext_vector_type(2))) _Float16;
using f16x8 = __attribute__((ext_vector_type(8))) _Float16;
using f32x4 = __attribute__((ext_vector_type(4))) float;
using f32x16 = __attribute__((ext_vector_type(16))) float;
using u32x4 = __attribute__((ext_vector_type(4))) uint32_t;

// global -> LDS direct copy, 16B per lane. LDS dest is wave-uniform base;
// HW writes base + lane*16 (guide m104/m108). Global src is per-lane.
DEVI void gload_lds16(const void* g, void* lds) {
  using GP = const __attribute__((address_space(1))) void*;
  using LP = __attribute__((address_space(3))) void*;
  __builtin_amdgcn_global_load_lds((GP)g, (LP)lds, 16, 0, 0);
}

DEVI uint32_t pack2h(float a, float b) {
  return (uint32_t)__half_as_ushort(__float2half(a)) |
         ((uint32_t)__half_as_ushort(__float2half(b)) << 16);
}

DEVI uint32_t cvtpk(float a, float b) {  // v_cvt_pkrtz_f16_f32
  auto h2 = __builtin_amdgcn_cvt_pkrtz(a, b);
  return __builtin_bit_cast(uint32_t, h2);
}

DEVI void plswap(uint32_t& a, uint32_t& b) {  // v_permlane32_swap_b32 (distinct values only)
  asm volatile("v_permlane32_swap_b32 %0, %1" : "+v"(a), "+v"(b));
}

DEVI float dot2acc(uint32_t w, f16x2 one, float c) {  // v_dot2_f32_f16
  return __builtin_amdgcn_fdot2(__builtin_bit_cast(f16x2, w), one, c, false);
}

DEVI float fmax3(float a, float b, float c) { return fmaxf(fmaxf(a, b), c); }

// ---------------- f32 -> f16 convert (vectorized, G13) ----------------
__global__ __launch_bounds__(256) void cvt_f32_f16(const float* __restrict__ in,
                                                   __half* __restrict__ out, int n8) {
  int i = blockIdx.x * 256 + threadIdx.x;
  if (i >= n8) return;
  float4 a = ((const float4*)in)[i * 2];
  float4 b = ((const float4*)in)[i * 2 + 1];
  uint4 u;
  u.x = pack2h(a.x, a.y);
  u.y = pack2h(a.z, a.w);
  u.z = pack2h(b.x, b.y);
  u.w = pack2h(b.z, b.w);
  ((uint4*)out)[i] = u;
}

// ---------------- GEMM: C[M][N] = A[M][K] * B[N][K]^T, f16 in, f32 acc ----------------
// 128x128 tile, BK=32, 4 waves (2x2), 16x16x32 f16 MFMA. (unchanged)
DEVI void store_c(__half* p, float v) { *p = __float2half(v); }
DEVI void store_c(float* p, float v) { *p = v; }

template <typename OT>
__global__ __launch_bounds__(256) void gemm_bt(const __half* __restrict__ A,
                                               const __half* __restrict__ B,
                                               OT* __restrict__ C, int M, int N, int K) {
  __shared__ __half As[128 * 32];
  __shared__ __half Bs[128 * 32];
  const int tid = threadIdx.x;
  const int w = tid >> 6, l = tid & 63;
  const int wm = w >> 1, wn = w & 1;
  const int m16 = l & 15, g = l >> 4;
  const int row0 = blockIdx.y * 128, col0 = blockIdx.x * 128;

  const int srow = l >> 2;
  const int ks = ((l & 3) ^ (srow & 3)) * 8;  // f16 elements

  f32x4 acc[4][4] = {};

  for (int kt = 0; kt < K; kt += 32) {
    __syncthreads();
#pragma unroll
    for (int i = 0; i < 2; ++i) {
      int c = w * 2 + i;
      int r = c * 16 + srow;
      gload_lds16(A + (size_t)(row0 + r) * K + kt + ks, (char*)As + c * 1024);
      gload_lds16(B + (size_t)(col0 + r) * K + kt + ks, (char*)Bs + c * 1024);
    }
    __syncthreads();
    f16x8 aF[4], bF[4];
#pragma unroll
    for (int mi = 0; mi < 4; ++mi) {
      int r = wm * 64 + mi * 16 + m16;
      aF[mi] = *(const f16x8*)((const char*)As + r * 64 + ((g << 4) ^ ((r & 3) << 4)));
    }
#pragma unroll
    for (int ni = 0; ni < 4; ++ni) {
      int r = wn * 64 + ni * 16 + m16;
      bF[ni] = *(const f16x8*)((const char*)Bs + r * 64 + ((g << 4) ^ ((r & 3) << 4)));
    }
#pragma unroll
    for (int mi = 0; mi < 4; ++mi)
#pragma unroll
      for (int ni = 0; ni < 4; ++ni)
        acc[mi][ni] = __builtin_amdgcn_mfma_f32_16x16x32_f16(aF[mi], bF[ni], acc[mi][ni], 0, 0, 0);
  }

#pragma unroll
  for (int mi = 0; mi < 4; ++mi)
#pragma unroll
    for (int ni = 0; ni < 4; ++ni)
#pragma unroll
      for (int j = 0; j < 4; ++j) {
        int r = row0 + wm * 64 + mi * 16 + g * 4 + j;
        int cc = col0 + wn * 64 + ni * 16 + m16;
        store_c(&C[(size_t)r * N + cc], acc[mi][ni][j]);
      }
}

// ---------------- RoPE + scatter to per-head layout ----------------
// qkv: [8192][3072] f16 (row = b*2048+n, col = s*1024 + h*64 + d)
// outputs: qr/kr [64 bh][2048 n][64 d]; vr TRANSPOSED [64 bh][64 d][2048 n].
// q pre-scaled by log2(e)/8 so attn uses exp2 with no per-element scale.
__global__ __launch_bounds__(256) void rope_scatter(const __half* __restrict__ qkv,
                                                    const float* __restrict__ rot,
                                                    __half* __restrict__ qr,
                                                    __half* __restrict__ kr,
                                                    __half* __restrict__ vr) {
  int t = blockIdx.x * 256 + threadIdx.x;  // 3*64*2048 threads
  int s = t >> 17;
  int rem = t & 131071;
  int bh = rem >> 11;
  int n = rem & 2047;
  int b = bh >> 4, h = bh & 15;
  const __half* src = qkv + (size_t)(b * 2048 + n) * 3072 + s * 1024 + h * 64;
  if (s == 2) {
    // transposed store: vr[bh][d][n]; scalar stores, coalesced across lanes
    __half* vdst = vr + ((size_t)bh * 64) * 2048 + n;
#pragma unroll
    for (int c = 0; c < 8; ++c) {
      f16x8 vv = ((const f16x8*)src)[c];
#pragma unroll
      for (int j = 0; j < 8; ++j) vdst[(size_t)(c * 8 + j) * 2048] = vv[j];
    }
    return;
  }
  __half* dst = (s == 0 ? qr : kr) + ((size_t)bh * 2048 + n) * 64;
  const float sc = (s == 0) ? 0.18033688011112042f : 1.0f;  // log2(e)/sqrt(64)
  const float* rp = rot + n * 64;
#pragma unroll
  for (int c = 0; c < 4; ++c) {
    f16x8 lo = ((const f16x8*)src)[c];      // d = 8c .. 8c+7
    f16x8 hi = ((const f16x8*)src)[c + 4];  // d+32
    float ol[8], oh[8];
#pragma unroll
    for (int j = 0; j < 8; ++j) {
      int d = c * 8 + j;
      float tl = (float)lo[j], th = (float)hi[j];
      float s0, c0, s1, c1;
      __sincosf(rp[d], &s0, &c0);
      __sincosf(rp[d + 32], &s1, &c1);
      ol[j] = (tl * c0 - th * s0) * sc;
      oh[j] = (th * c1 + tl * s1) * sc;
    }
    uint4 ulo, uhi;
    ulo.x = pack2h(ol[0], ol[1]); ulo.y = pack2h(ol[2], ol[3]);
    ulo.z = pack2h(ol[4], ol[5]); ulo.w = pack2h(ol[6], ol[7]);
    uhi.x = pack2h(oh[0], oh[1]); uhi.y = pack2h(oh[2], oh[3]);
    uhi.z = pack2h(oh[4], oh[5]); uhi.w = pack2h(oh[6], oh[7]);
    ((uint4*)dst)[c] = ulo;
    ((uint4*)dst)[c + 4] = uhi;
  }
}

// ---------------- Flash attention fwd, swapped-QK 32x32 ----------------
// R8 = R5's PASSING structure (inline kvb loop, shfl_xor(32) reductions, proven
// plswap W-redistribution) + ONLY two deltas:
//  (1) V relayout [2 kvh][64 d][128B rows], slot ^= d&7 — full 3-bit bank-quad
//      spread (R5's 64B rows had 2 bits -> 2-way conflict, 16.8M cycles).
//      Mapping equivalence to R5 proven by coordinate walk (v00 -> kv
//      kvb*32+hi*8+j at d=q/q+32, identical to R5's vb00 decode).
//  (2) __syncthreads() tile boundaries (superset of R5's asm-vmcnt+s_barrier).
// NO plswapf-on-copies (R6/R7's unproven reduction idiom), NO QK reorder.
__global__ __launch_bounds__(256, 2) void attn_fwd(const __half* __restrict__ qr,
                                                   const __half* __restrict__ kr,
                                                   const __half* __restrict__ vr,
                                                   __half* __restrict__ out) {
  __shared__ __half K2[2 * 128 * 64];  // 32 KB
  __shared__ __half V2[2 * 64 * 128];  // 32 KB

  int bid = blockIdx.x;
  bid = (bid & 7) * 128 + (bid >> 3);  // XCD swizzle: same-head blocks share an XCD L2
  const int bh = bid >> 4;
  const int q0 = (bid & 15) * 128;
  const int tid = threadIdx.x;
  const int w = tid >> 6, l = tid & 63;
  const int q = l & 31, hi = l >> 5;
  const size_t headoff = (size_t)bh * 2048 * 64;

  // Q B-frags: Q[q0+w*32+q][c*16 + hi*8 .. +7], c=0..3 (held all block)
  f16x8 qB[4];
  {
    const __half* qp = qr + headoff + (size_t)(q0 + w * 32 + q) * 64 + hi * 8;
#pragma unroll
    for (int c = 0; c < 4; ++c) qB[c] = *(const f16x8*)(qp + c * 16);
  }

  // hoisted lane-invariant LDS read offsets
  int kf[4];  // K A-frag: byte = Kb + kvb*4096 + kf[c]
#pragma unroll
  for (int c = 0; c < 4; ++c)
    kf[c] = q * 128 + 16 * (hi ^ (q & 1)) + 32 * (c ^ ((q >> 1) & 3));
  // V B-frag: byte = Vb + (kvb>>1)*8192 + (vbase ^ (kvb&1)<<6 [^32 hi16]) [+4096 d1]
  const int vbase = q * 128 + ((hi ^ (q & 7)) << 4);

  // staging coords
  const int krow_l = l >> 3, kslot = l & 7;
  const __half* kb = kr + headoff;
  const __half* vb = vr + (size_t)bh * 64 * 2048;

  auto STAGE = [&](int buf, int kv0) {
#pragma unroll
    for (int i = 0; i < 4; ++i) {  // K [128 kv][64 d], slot ^= kv&7
      int c = w * 4 + i;
      int row = c * 8 + krow_l;
      gload_lds16(kb + (size_t)(kv0 + row) * 64 + ((kslot ^ (row & 7)) * 8),
                  (char*)K2 + buf * 16384 + c * 1024);
    }
#pragma unroll
    for (int i = 0; i < 4; ++i) {  // V [2 kvh][64 d][64 kv], slot ^= d&7
      int c = w * 4 + i;
      int d = (c & 7) * 8 + (l >> 3);
      gload_lds16(vb + (size_t)d * 2048 + kv0 + (c >> 3) * 64 + (((l & 7) ^ (l >> 3)) * 8),
                  (char*)V2 + buf * 16384 + c * 1024);
    }
  };

  const f16x2 one2 = {(_Float16)1.f, (_Float16)1.f};
  f32x16 o0 = {}, o1 = {};  // O[q-rows][d0=q / d1=q+32]
  float mreg = -1e30f, lreg = 0.f;

  // prologue: stage tile 0; __syncthreads drains vmcnt(0)+lgkmcnt(0) and fences
  STAGE(0, 0);
  __syncthreads();

  for (int t = 0; t < 16; ++t) {
    const int buf = t & 1;
    if (t < 15) STAGE(buf ^ 1, (t + 1) * 128);  // prefetch next tile (overlaps compute)

    const char* Kb = (const char*)K2 + buf * 16384;
    const char* Vb = (const char*)V2 + buf * 16384;
#pragma unroll
    for (int kvb = 0; kvb < 4; ++kvb) {
      // ---- S^T[kv 32][q 32] = K * Q^T
      f32x16 s = {};
      __builtin_amdgcn_s_setprio(1);
#pragma unroll
      for (int c = 0; c < 4; ++c) {
        f16x8 kA = *(const f16x8*)(Kb + kvb * 4096 + kf[c]);
        s = __builtin_amdgcn_mfma_f32_32x32x16_f16(kA, qB[c], s, 0, 0, 0);
      }
      __builtin_amdgcn_s_setprio(0);

      // ---- in-register online softmax (lane owns q-col l&31, 16 kv rows)
      float mt = fmax3(s[0], s[1], s[2]);
      mt = fmax3(mt, s[3], s[4]);
      mt = fmax3(mt, s[5], s[6]);
      mt = fmax3(mt, s[7], s[8]);
      mt = fmax3(mt, s[9], s[10]);
      mt = fmax3(mt, s[11], s[12]);
      mt = fmax3(mt, s[13], s[14]);
      mt = fmaxf(mt, s[15]);
      mt = fmaxf(mt, __shfl_xor(mt, 32));  // proven cross-half reduce (R5)
      if (__any(mt - mreg > 8.f)) {  // defer-max (T13)
        float mnew = fmaxf(mreg, mt);
        float alpha = __builtin_amdgcn_exp2f(mreg - mnew);
        lreg *= alpha;
        o0 *= alpha;
        o1 *= alpha;
        mreg = mnew;
      }
      uint32_t W[8];
      float rs = 0.f;
#pragma unroll
      for (int i2 = 0; i2 < 8; ++i2) {  // exp2 + pack + fused row-sum (fdot2)
        float e0 = __builtin_amdgcn_exp2f(s[2 * i2] - mreg);
        float e1 = __builtin_amdgcn_exp2f(s[2 * i2 + 1] - mreg);
        W[i2] = cvtpk(e0, e1);
        rs = dot2acc(W[i2], one2, rs);
      }
      rs += __shfl_xor(rs, 32);  // proven cross-half reduce (R5)
      lreg += rs;

      // ---- P-frag redistribution: 4 permlane32_swap (proven in R5)
      plswap(W[0], W[2]);
      plswap(W[1], W[3]);
      plswap(W[4], W[6]);
      plswap(W[5], W[7]);
      u32x4 f0 = {W[0], W[1], W[2], W[3]};
      u32x4 f1 = {W[4], W[5], W[6], W[7]};
      f16x8 pA0 = __builtin_bit_cast(f16x8, f0);  // kv kvb*32 + 0..15
      f16x8 pA1 = __builtin_bit_cast(f16x8, f1);  // kv kvb*32 + 16..31

      // ---- PV: O += P * V   (V reads from 128B-row layout)
      const char* Vk = Vb + (kvb >> 1) * 8192;
      const int vx = vbase ^ ((kvb & 1) << 6);   // kv lo-16 slot
      const int vx2 = vx ^ 32;                   // kv hi-16 slot
      f16x8 v00 = *(const f16x8*)(Vk + vx);
      f16x8 v01 = *(const f16x8*)(Vk + vx + 4096);
      f16x8 v10 = *(const f16x8*)(Vk + vx2);
      f16x8 v11 = *(const f16x8*)(Vk + vx2 + 4096);
      __builtin_amdgcn_s_setprio(1);
      o0 = __builtin_amdgcn_mfma_f32_32x32x16_f16(pA0, v00, o0, 0, 0, 0);
      o1 = __builtin_amdgcn_mfma_f32_32x32x16_f16(pA0, v01, o1, 0, 0, 0);
      o0 = __builtin_amdgcn_mfma_f32_32x32x16_f16(pA1, v10, o0, 0, 0, 0);
      o1 = __builtin_amdgcn_mfma_f32_32x32x16_f16(pA1, v11, o1, 0, 0, 0);
      __builtin_amdgcn_s_setprio(0);
    }

    __syncthreads();  // fence + barrier + counter drain: next tile fully in LDS
  }

  // ---- epilogue: O reg r holds q-row (r&3)+8*(r>>2)+4*hi, d-col q (+0/32)
  const int b = bh >> 4, hh = bh & 15;
  float invl = 1.0f / lreg;
#pragma unroll
  for (int r = 0; r < 16; ++r) {
    int qrow = (r & 3) + 8 * (r >> 2) + 4 * hi;
    float inv = __shfl(invl, qrow);
    __half* orow = out + (size_t)(b * 2048 + q0 + w * 32 + qrow) * 1024 + hh * 64;
    orow[q] = __float2half(o0[r] * inv);
    orow[32 + q] = __float2half(o1[r] * inv);
  }
}

// ---------------- launch ----------------
extern "C" void kernel_launch(void* const* d_in, const int* in_sizes, int n_in,
                              void* d_out, int out_size, void* d_ws, size_t ws_size,
                              hipStream_t stream) {
  const float* x    = (const float*)d_in[0];  // [4,2048,1024]
  const float* rot  = (const float*)d_in[1];  // [2048,64]
  const float* wqkv = (const float*)d_in[2];  // [3072,1024]
  const float* wout = (const float*)d_in[3];  // [1024,1024]
  float* out = (float*)d_out;
  char* ws = (char*)d_ws;

  __half* xb    = (__half*)(ws + 0);               // 16 MB (reused as qr)
  __half* wqkvb = (__half*)(ws + (16ull << 20));   // 6 MB
  __half* woutb = (__half*)(ws + (22ull << 20));   // 2 MB
  __half* qkv   = (__half*)(ws + (24ull << 20));   // 48 MB (reused as attn_out)
  __half* kr    = (__half*)(ws + (72ull << 20));   // 16 MB
  __half* vr    = (__half*)(ws + (88ull << 20));   // 16 MB (TRANSPOSED [bh][d][n])
  __half* qr    = xb;
  __half* ao    = qkv;

  cvt_f32_f16<<<4096, 256, 0, stream>>>(x, xb, 1048576);
  cvt_f32_f16<<<1536, 256, 0, stream>>>(wqkv, wqkvb, 393216);
  cvt_f32_f16<<<512, 256, 0, stream>>>(wout, woutb, 131072);
  // qkv = xb @ wqkvb^T   [8192,3072]
  gemm_bt<__half><<<dim3(24, 64), 256, 0, stream>>>(xb, wqkvb, qkv, 8192, 3072, 1024);
  rope_scatter<<<1536, 256, 0, stream>>>(qkv, rot, qr, kr, vr);
  attn_fwd<<<1024, 256, 0, stream>>>(qr, kr, vr, ao);
  // out = ao @ woutb^T   [8192,1024] f32
  gemm_bt<float><<<dim3(8, 64), 256, 0, stream>>>(ao, woutb, out, 8192, 1024, 1024);
}